// Round 1
// baseline (775.941 us; speedup 1.0000x reference)
//
#include <hip/hip_runtime.h>

#define D 256
#define NODES_PER_WAVE 64

// Fused: scores = x@W + b, e = exp(score) (no max-subtraction needed: scores ~N(0,1),
// max ~5.2, exp well within fp32), accumulate U[seg] = sum e*x in registers (sorted
// batch_index => flush via atomicAdd only on segment change), Z = sum e via one
// atomic per wave. Epilogue kernel divides out by Z.
__global__ __launch_bounds__(256) void attn_pool_fused(
    const float* __restrict__ x, const int* __restrict__ idx,
    const float* __restrict__ W, const float* __restrict__ bias_p,
    float* __restrict__ out, float* __restrict__ zsum, int N) {
  const int tid  = blockIdx.x * blockDim.x + threadIdx.x;
  const int wave = tid >> 6;
  const int lane = threadIdx.x & 63;
  const long start = (long)wave * NODES_PER_WAVE;
  if (start >= N) return;
  const int count = (int)min((long)NODES_PER_WAVE, (long)N - start);

  // lane l owns columns [4l, 4l+3]
  const float4 w4 = reinterpret_cast<const float4*>(W)[lane];
  const float bias = *bias_p;

  // one coalesced load covers all 64 node indices for this wave
  int nidx = (start + lane < N) ? idx[start + lane] : idx[N - 1];

  float4 acc = make_float4(0.f, 0.f, 0.f, 0.f);
  int cur_seg = __shfl(nidx, 0);
  float zpart = 0.f;

  for (int i = 0; i < count; ++i) {
    const float4 x4 =
        reinterpret_cast<const float4*>(x + (start + i) * (long)D)[lane];
    float s = x4.x * w4.x + x4.y * w4.y + x4.z * w4.z + x4.w * w4.w;
#pragma unroll
    for (int o = 1; o < 64; o <<= 1) s += __shfl_xor(s, o);
    s += bias;
    const float e = expf(s);  // identical in all lanes
    zpart += e;

    const int seg = __shfl(nidx, i);
    if (seg != cur_seg) {
      float* op = out + (long)cur_seg * D + lane * 4;
      atomicAdd(op + 0, acc.x);
      atomicAdd(op + 1, acc.y);
      atomicAdd(op + 2, acc.z);
      atomicAdd(op + 3, acc.w);
      acc = make_float4(0.f, 0.f, 0.f, 0.f);
      cur_seg = seg;
    }
    acc.x += e * x4.x;
    acc.y += e * x4.y;
    acc.z += e * x4.z;
    acc.w += e * x4.w;
  }
  float* op = out + (long)cur_seg * D + lane * 4;
  atomicAdd(op + 0, acc.x);
  atomicAdd(op + 1, acc.y);
  atomicAdd(op + 2, acc.z);
  atomicAdd(op + 3, acc.w);
  if (lane == 0) atomicAdd(zsum, zpart);
}

__global__ __launch_bounds__(256) void attn_pool_scale(
    float* __restrict__ out, const float* __restrict__ zsum, int n4) {
  const int i = blockIdx.x * blockDim.x + threadIdx.x;
  if (i >= n4) return;
  const float inv = 1.0f / *zsum;
  float4 v = reinterpret_cast<float4*>(out)[i];
  v.x *= inv; v.y *= inv; v.z *= inv; v.w *= inv;
  reinterpret_cast<float4*>(out)[i] = v;
}

extern "C" void kernel_launch(void* const* d_in, const int* in_sizes, int n_in,
                              void* d_out, int out_size, void* d_ws, size_t ws_size,
                              hipStream_t stream) {
  const float* x   = (const float*)d_in[0];
  const int*   idx = (const int*)d_in[1];
  // d_in[2] = num_segments (scalar int) — implied by out_size
  const float* W   = (const float*)d_in[3];
  const float* b   = (const float*)d_in[4];
  float* out  = (float*)d_out;
  float* zsum = (float*)d_ws;

  const int N = in_sizes[1];

  hipMemsetAsync(out, 0, (size_t)out_size * sizeof(float), stream);
  hipMemsetAsync(zsum, 0, sizeof(float), stream);

  const int num_waves = (N + NODES_PER_WAVE - 1) / NODES_PER_WAVE;
  const int block = 256;
  const int grid = (num_waves * 64 + block - 1) / block;
  attn_pool_fused<<<grid, block, 0, stream>>>(x, idx, W, b, out, zsum, N);

  const int n4 = out_size / 4;
  attn_pool_scale<<<(n4 + block - 1) / block, block, 0, stream>>>(out, zsum, n4);
}